// Round 10
// baseline (407.971 us; speedup 1.0000x reference)
//
#include <hip/hip_runtime.h>
#include <hip/hip_bf16.h>

// KAN layer as augmented GEMM:
//   Af[b, c*1024+i] = c==0 ? silu(x[b,i]) : basis_{c-1}(x[b,i])   (bf16)
//   Wf[o, c*1024+i] = c==0 ? base_w[o,i]  : spline_w[o,i,c-1]     (bf16)
//   out = Af @ Wf^T  (fp32 accum via MFMA)
//
// GEMM (round-4 skeleton + B-in-registers):
//   256x128 tile, BK=64, 8 waves 2Mx2N (64x64/wave), 2 phases x 16 MFMA,
//   lgkmcnt(0)+sched_barrier rhythm (proven 48% MfmaUtil). B-fragments
//   load global->VGPR (line-exact coalescing), reg-double-buffered via
//   2x-unrolled K-loop -> LDS traffic 176KB->96KB/tile (bound flips to
//   MFMA). A stays global_load_lds ring-3 (96KB, 2-tile lead). T1 maps
//   bn = XCD id -> each XCD's 2.36MB B-panel is L2-resident. Counted
//   vmcnt(4) at tile top (drains b(t)+A(t), keeps A(t+1)); vmcnt(0) only
//   at the final tile. (row&7) 16B-slot XOR swizzle for A (0-conflict).
//   No split-K, no reduce. Grid 256 = 1 block/CU.
#define B_DIM 8192
#define I_DIM 1024
#define O_DIM 1024
#define K_DIM 9216   // 9 * 1024

#define BM 256
#define BN 128
#define BK 64
#define NKT (K_DIM / BK)   // 144

typedef unsigned short ushort_t;
typedef __attribute__((ext_vector_type(8))) short short8;
typedef __attribute__((ext_vector_type(4))) float f32x4;

#define MFMA(a, b, c) __builtin_amdgcn_mfma_f32_16x16x32_bf16((a), (b), (c), 0, 0, 0)

__device__ __forceinline__ ushort_t f2bf(float f) {
    unsigned u = __float_as_uint(f);
    unsigned r = 0x7fffu + ((u >> 16) & 1u);
    return (ushort_t)((u + r) >> 16);
}

__device__ __forceinline__ void llds16(const ushort_t* g, ushort_t* l) {
    __builtin_amdgcn_global_load_lds(
        (const __attribute__((address_space(1))) unsigned int*)g,
        (__attribute__((address_space(3))) unsigned int*)l,
        16, 0, 0);
}

// ---------------- expansion: weights ----------------
__global__ __launch_bounds__(256) void expand_w_kernel(
        const float* __restrict__ bw, const float* __restrict__ sw,
        ushort_t* __restrict__ Wf) {
    int idx = blockIdx.x * 256 + threadIdx.x;   // one thread: (o, 2 consecutive i)
    int o = idx >> 9;
    int i = (idx & 511) << 1;
    ushort_t* out = Wf + (size_t)o * K_DIM + i;
    const float* bp = bw + ((size_t)o << 10) + i;
    *(unsigned*)out = (unsigned)f2bf(bp[0]) | ((unsigned)f2bf(bp[1]) << 16);
    const float* sp = sw + (((size_t)o << 10) + i) * 8;   // 16 contiguous floats
    float v[16];
    #pragma unroll
    for (int n = 0; n < 16; ++n) v[n] = sp[n];
    #pragma unroll
    for (int n = 0; n < 8; ++n)
        *(unsigned*)(out + (size_t)(n + 1) * 1024) =
            (unsigned)f2bf(v[n]) | ((unsigned)f2bf(v[8 + n]) << 16);
}

// ---------------- expansion: activations ----------------
__global__ __launch_bounds__(256) void expand_a_kernel(
        const float* __restrict__ x, ushort_t* __restrict__ Af) {
    int idx = blockIdx.x * 256 + threadIdx.x;   // one thread: (b, 2 consecutive i)
    int b = idx >> 9;
    int i = (idx & 511) << 1;
    const float* xp = x + ((size_t)b << 10) + i;
    float x0 = xp[0], x1 = xp[1];
    ushort_t* out = Af + (size_t)b * K_DIM + i;
    float s0 = x0 / (1.0f + __expf(-x0));
    float s1 = x1 / (1.0f + __expf(-x1));
    *(unsigned*)out = (unsigned)f2bf(s0) | ((unsigned)f2bf(s1) << 16);
    // quadratic B-spline basis, uniform knots -9..9 step 1.8
    float t0 = (x0 + 9.0f) * (1.0f / 1.8f);
    float t1 = (x1 + 9.0f) * (1.0f / 1.8f);
    float fj0 = floorf(t0), fj1 = floorf(t1);
    int j0 = (int)fj0, j1 = (int)fj1;
    float u0 = t0 - fj0, u1 = t1 - fj1;
    float p0 = 0.5f * (1.f - u0) * (1.f - u0);
    float p1 = 0.5f * (-2.f * u0 * u0 + 2.f * u0 + 1.f);
    float p2 = 0.5f * u0 * u0;
    float q0 = 0.5f * (1.f - u1) * (1.f - u1);
    float q1 = 0.5f * (-2.f * u1 * u1 + 2.f * u1 + 1.f);
    float q2 = 0.5f * u1 * u1;
    #pragma unroll
    for (int n = 0; n < 8; ++n) {
        float v0 = (n == j0 - 2) ? p0 : (n == j0 - 1) ? p1 : (n == j0) ? p2 : 0.f;
        float v1 = (n == j1 - 2) ? q0 : (n == j1 - 1) ? q1 : (n == j1) ? q2 : 0.f;
        *(unsigned*)(out + (size_t)(n + 1) * 1024) =
            (unsigned)f2bf(v0) | ((unsigned)f2bf(v1) << 16);
    }
}

// ---------------- GEMM: out[M=8192, N=1024] = Af[M,K] * Wf[N,K]^T ----------------
__global__ __launch_bounds__(512) void gemm_bt(
        const ushort_t* __restrict__ Af,
        const ushort_t* __restrict__ Wf,
        float* __restrict__ out) {
    // A-only ring-3: 3 x 32KB = 96KB LDS (B never touches LDS)
    __shared__ __align__(16) ushort_t As[3][BM * BK];

    const int tid = threadIdx.x;

    // T1 (bn = XCD id): wgid = xcd*32 + j; bn = xcd -> 2.36MB B-panel
    // L2-resident per XCD; bm = j (A read exactly once, no reuse needed).
    const int orig = blockIdx.x;
    const int wgid = (orig & 7) * 32 + (orig >> 3);
    const int bn = wgid >> 5;               // 0..7  (== orig & 7)
    const int bm = wgid & 31;               // 0..31
    const int mBase = bm * BM, nBase = bn * BN;

    const int lane = tid & 63;
    const int w = tid >> 6;                 // 8 waves: 4M x 2N -> 64x64 per wave
    const int wr = (w >> 1) * 64, wc = (w & 1) * 64;
    const int fr = lane & 15;
    const int kg = lane >> 4;               // k-group 0..3

    // A staging: 512 threads x 16B = 8KB/round = 64 rows of 128B; 4 rounds.
    // T2 swizzle: 16B slot ^= (row&7); source pre-swizzled, LDS dest linear.
    const int srow = tid >> 3;                                  // 0..63
    const int scolE = (((tid & 7) ^ (srow & 7)) << 3);          // pre-swizzled source col
    const int sdst = (tid & ~63) * 8;                           // wave-uniform elem offset

    auto stageA = [&](int t, int buf) {
        #pragma unroll
        for (int rnd = 0; rnd < 4; ++rnd) {
            const ushort_t* g = Af + (size_t)(mBase + rnd * 64 + srow) * K_DIM
                                   + (size_t)t * BK + scolE;
            llds16(g, &As[buf][rnd * 4096 + sdst]);
        }
    };

    // B-fragment loads: global -> VGPR. Per instr: 16 rows x 4 kg = whole
    // 64B lines, fully consumed. b[n][kk] covers rows wc+n*16+fr, k kk*32+kg*8.
    const ushort_t* Wbase = Wf + (size_t)(nBase + wc + fr) * K_DIM + kg * 8;
    auto bload = [&](int t, short8 (&b)[4][2]) {
        #pragma unroll
        for (int n = 0; n < 4; ++n)
            #pragma unroll
            for (int kk = 0; kk < 2; ++kk)
                b[n][kk] = *(const short8*)(Wbase + (size_t)n * 16 * K_DIM
                                                  + (size_t)t * BK + kk * 32);
    };

    // A read-side swizzled 16B-slot offsets (row&7 == fr&7)
    const int swz0 = ((kg ^ (fr & 7)) << 3);          // kk = 0
    const int swz1 = (((4 + kg) ^ (fr & 7)) << 3);    // kk = 1

    f32x4 acc[4][4];
    #pragma unroll
    for (int m = 0; m < 4; ++m)
        #pragma unroll
        for (int n = 0; n < 4; ++n) acc[m][n] = (f32x4){0.f, 0.f, 0.f, 0.f};

    short8 bA[4][2], bB[4][2];   // register-double-buffered B fragments

    // prologue FIFO: b(0)[8], A(0)[4], A(1)[4]  -> tile0's vmcnt(4) drains b(0),A(0)
    bload(0, bA);
    __builtin_amdgcn_sched_barrier(0);
    stageA(0, 0);
    stageA(1, 1);

    int ca = 0;   // A ring slot holding tile t
    // per-tile body (r4 rhythm): 2 phases x 16 MFMA; bc = B(t) regs, bnx = B(t+1) dest
    auto tile = [&](int t, short8 (&bc)[4][2], short8 (&bnx)[4][2]) {
        if (t == NKT - 1) asm volatile("s_waitcnt vmcnt(0)" ::: "memory");
        else              asm volatile("s_waitcnt vmcnt(4)" ::: "memory");
        __builtin_amdgcn_s_barrier();

        const ushort_t* A_ = As[ca];
        const int pa = (ca >= 1) ? ca - 1 : 2;   // (ca+2)%3

        // ---- phase 1: issue b(t+1); read a rows 0-1; 16 MFMA (m=0,1) ----
        if (t + 1 < NKT) bload(t + 1, bnx);
        __builtin_amdgcn_sched_barrier(0);
        short8 a1[2][2];
        #pragma unroll
        for (int i = 0; i < 2; ++i) {
            int arow = (wr + i * 16 + fr) * BK;
            a1[i][0] = *(const short8*)&A_[arow + swz0];
            a1[i][1] = *(const short8*)&A_[arow + swz1];
        }
        asm volatile("s_waitcnt lgkmcnt(0)" ::: "memory");
        __builtin_amdgcn_sched_barrier(0);
        __builtin_amdgcn_s_setprio(1);
        #pragma unroll
        for (int i = 0; i < 2; ++i)
            #pragma unroll
            for (int n = 0; n < 4; ++n) {
                acc[i][n] = MFMA(a1[i][0], bc[n][0], acc[i][n]);
                acc[i][n] = MFMA(a1[i][1], bc[n][1], acc[i][n]);
            }
        __builtin_amdgcn_s_setprio(0);
        __builtin_amdgcn_s_barrier();

        // ---- phase 2: stage A(t+2); read a rows 2-3; 16 MFMA (m=2,3) ----
        if (t + 2 < NKT) stageA(t + 2, pa);
        __builtin_amdgcn_sched_barrier(0);
        short8 a2[2][2];
        #pragma unroll
        for (int i = 0; i < 2; ++i) {
            int arow = (wr + (2 + i) * 16 + fr) * BK;
            a2[i][0] = *(const short8*)&A_[arow + swz0];
            a2[i][1] = *(const short8*)&A_[arow + swz1];
        }
        asm volatile("s_waitcnt lgkmcnt(0)" ::: "memory");
        __builtin_amdgcn_sched_barrier(0);
        __builtin_amdgcn_s_setprio(1);
        #pragma unroll
        for (int i = 0; i < 2; ++i)
            #pragma unroll
            for (int n = 0; n < 4; ++n) {
                acc[2 + i][n] = MFMA(a2[i][0], bc[n][0], acc[2 + i][n]);
                acc[2 + i][n] = MFMA(a2[i][1], bc[n][1], acc[2 + i][n]);
            }
        __builtin_amdgcn_s_setprio(0);

        ca = (ca + 1 == 3) ? 0 : ca + 1;
    };

    for (int t = 0; t < NKT; t += 2) {   // NKT=144 even: reg ping-pong via unroll-2
        tile(t, bA, bB);
        tile(t + 1, bB, bA);
    }

    // epilogue: C/D layout col=lane&15, row=(lane>>4)*4+r
    const int orow = (lane >> 4) * 4;
    const int ocol = lane & 15;
    #pragma unroll
    for (int m = 0; m < 4; ++m)
        #pragma unroll
        for (int n = 0; n < 4; ++n) {
            size_t base = (size_t)(mBase + wr + m * 16 + orow) * O_DIM
                        + (nBase + wc + n * 16 + ocol);
            #pragma unroll
            for (int r = 0; r < 4; ++r)
                out[base + (size_t)r * O_DIM] = acc[m][n][r];
        }
}

extern "C" void kernel_launch(void* const* d_in, const int* in_sizes, int n_in,
                              void* d_out, int out_size, void* d_ws, size_t ws_size,
                              hipStream_t stream) {
    const float* x  = (const float*)d_in[0];
    const float* bw = (const float*)d_in[1];
    const float* sw = (const float*)d_in[2];
    float* out = (float*)d_out;

    // ws layout: Wf [1024 x 9216] bf16 (18.9 MB) then Af [8192 x 9216] bf16 (151 MB)
    ushort_t* Wf = (ushort_t*)d_ws;
    ushort_t* Af = Wf + (size_t)O_DIM * K_DIM;

    expand_w_kernel<<<(O_DIM * I_DIM / 2) / 256, 256, 0, stream>>>(bw, sw, Wf);
    expand_a_kernel<<<(B_DIM * I_DIM / 2) / 256, 256, 0, stream>>>(x, Af);
    gemm_bt<<<(B_DIM / BM) * (O_DIM / BN), 512, 0, stream>>>(Af, Wf, out);
}

// Round 11
// 296.585 us; speedup vs baseline: 1.3756x; 1.3756x over previous
//
#include <hip/hip_runtime.h>
#include <hip/hip_bf16.h>

// KAN layer as augmented GEMM:
//   Af2[frag-ordered] <- c==0 ? silu(x) : basis_{c-1}(x)   (bf16)
//   Wf[o, c*1024+i]   <- c==0 ? base_w  : spline_w[:,:,c-1] (bf16, row-major)
//   out = A @ W^T  (fp32 accum via MFMA)
//
// GEMM (round-4 skeleton + A-in-registers):
//   256x128, BK=64, 8 waves (wr in {0,64,128,192} x wc in {0,64} -> 64x64/wave,
//   r4 epilogue). A-fragments load global->VGPR from FRAGMENT-ORDERED Af2:
//   16row x 64k blocks stored [kk][kg][fr][8] so each a-load instr is 64
//   lanes x 16B = 1KB contiguous. Reg ping-pong via unroll-2. B stays
//   global_load_lds dbuf (32KB LDS) + (row&7) swizzle (0-conflict). Per
//   tile: ONE vmcnt(0)+barrier at top (issues have full-tile lead), then
//   8 b ds_reads, lgkmcnt(4) -> 16 MFMA, lgkmcnt(0) -> 16 MFMA. LDS/tile
//   176->80KB; MFMA waits only on 4-deep B reads. r4 XCD mapping (A
//   panels XCD-local). No split-K. Grid 256 = 1 block/CU.
#define B_DIM 8192
#define I_DIM 1024
#define O_DIM 1024
#define K_DIM 9216   // 9 * 1024

#define BM 256
#define BN 128
#define BK 64
#define NKT (K_DIM / BK)   // 144

typedef unsigned short ushort_t;
typedef __attribute__((ext_vector_type(8))) short short8;
typedef __attribute__((ext_vector_type(4))) float f32x4;

#define MFMA(a, b, c) __builtin_amdgcn_mfma_f32_16x16x32_bf16((a), (b), (c), 0, 0, 0)

__device__ __forceinline__ ushort_t f2bf(float f) {
    unsigned u = __float_as_uint(f);
    unsigned r = 0x7fffu + ((u >> 16) & 1u);
    return (ushort_t)((u + r) >> 16);
}

__device__ __forceinline__ void llds16(const ushort_t* g, ushort_t* l) {
    __builtin_amdgcn_global_load_lds(
        (const __attribute__((address_space(1))) unsigned int*)g,
        (__attribute__((address_space(3))) unsigned int*)l,
        16, 0, 0);
}

// ---------------- expansion: weights (row-major Wf, unchanged) ----------------
__global__ __launch_bounds__(256) void expand_w_kernel(
        const float* __restrict__ bw, const float* __restrict__ sw,
        ushort_t* __restrict__ Wf) {
    int idx = blockIdx.x * 256 + threadIdx.x;   // one thread: (o, 2 consecutive i)
    int o = idx >> 9;
    int i = (idx & 511) << 1;
    ushort_t* out = Wf + (size_t)o * K_DIM + i;
    const float* bp = bw + ((size_t)o << 10) + i;
    *(unsigned*)out = (unsigned)f2bf(bp[0]) | ((unsigned)f2bf(bp[1]) << 16);
    const float* sp = sw + (((size_t)o << 10) + i) * 8;   // 16 contiguous floats
    float v[16];
    #pragma unroll
    for (int n = 0; n < 16; ++n) v[n] = sp[n];
    #pragma unroll
    for (int n = 0; n < 8; ++n)
        *(unsigned*)(out + (size_t)(n + 1) * 1024) =
            (unsigned)f2bf(v[n]) | ((unsigned)f2bf(v[8 + n]) << 16);
}

// ---------------- expansion: activations -> FRAGMENT-ORDERED Af2 ----------------
// Block (r16 = b>>4, t = k>>6) of 16 rows x 64 k stored at (r16*NKT + t)*1024
// elems, in-block offset = ((kk*4+kg)*16 + fr)*8 + e  (kk=(k>>5)&1,
// kg=(k>>3)&3, fr=b&15, e=k&7). k = c*1024 + i -> k%64 == i%64.
__global__ __launch_bounds__(256) void expand_a_kernel(
        const float* __restrict__ x, ushort_t* __restrict__ Af2) {
    int idx = blockIdx.x * 256 + threadIdx.x;   // one thread: (b, 2 consecutive i)
    int b = idx >> 9;
    int i = (idx & 511) << 1;
    const float* xp = x + ((size_t)b << 10) + i;
    float x0 = xp[0], x1 = xp[1];
    // base elem offset for c=0 (t = i>>6); each c adds 16 blocks = 16384 elems
    ushort_t* out = Af2 + ((size_t)(b >> 4) * NKT + (i >> 6)) * 1024
                        + ((i >> 5) & 1) * 512 + ((i >> 3) & 3) * 128
                        + (b & 15) * 8 + (i & 7);
    float s0 = x0 / (1.0f + __expf(-x0));
    float s1 = x1 / (1.0f + __expf(-x1));
    *(unsigned*)out = (unsigned)f2bf(s0) | ((unsigned)f2bf(s1) << 16);
    // quadratic B-spline basis, uniform knots -9..9 step 1.8
    float t0 = (x0 + 9.0f) * (1.0f / 1.8f);
    float t1 = (x1 + 9.0f) * (1.0f / 1.8f);
    float fj0 = floorf(t0), fj1 = floorf(t1);
    int j0 = (int)fj0, j1 = (int)fj1;
    float u0 = t0 - fj0, u1 = t1 - fj1;
    float p0 = 0.5f * (1.f - u0) * (1.f - u0);
    float p1 = 0.5f * (-2.f * u0 * u0 + 2.f * u0 + 1.f);
    float p2 = 0.5f * u0 * u0;
    float q0 = 0.5f * (1.f - u1) * (1.f - u1);
    float q1 = 0.5f * (-2.f * u1 * u1 + 2.f * u1 + 1.f);
    float q2 = 0.5f * u1 * u1;
    #pragma unroll
    for (int n = 0; n < 8; ++n) {
        float v0 = (n == j0 - 2) ? p0 : (n == j0 - 1) ? p1 : (n == j0) ? p2 : 0.f;
        float v1 = (n == j1 - 2) ? q0 : (n == j1 - 1) ? q1 : (n == j1) ? q2 : 0.f;
        *(unsigned*)(out + (size_t)(n + 1) * 16384) =
            (unsigned)f2bf(v0) | ((unsigned)f2bf(v1) << 16);
    }
}

// ---------------- GEMM: out[M=8192, N=1024] = A[M,K] * W[N,K]^T ----------------
__global__ __launch_bounds__(512) void gemm_bt(
        const ushort_t* __restrict__ Af2,
        const ushort_t* __restrict__ Wf,
        float* __restrict__ out) {
    __shared__ __align__(16) ushort_t Bs[2][BN * BK];   // 2 x 16 KB

    const int tid = threadIdx.x;

    // T1 (r4 mapping): xcd gets 32 consecutive wgid = 4 bm x all 8 bn ->
    // A panels XCD-local (read once from HBM), Wf via L2/L3.
    const int orig = blockIdx.x;
    const int wgid = (orig & 7) * 32 + (orig >> 3);
    const int bm = wgid >> 3;               // 0..31
    const int bn = wgid & 7;                // 0..7
    const int mBase = bm * BM, nBase = bn * BN;

    const int lane = tid & 63;
    const int w = tid >> 6;                 // 8 waves: wr in {0,64,128,192}, wc in {0,64}
    const int wr = (w >> 1) * 64, wc = (w & 1) * 64;
    const int fr = lane & 15;
    const int kg = lane >> 4;               // k-group 0..3

    // B staging: 512 threads x 16B = 8KB/round = 64 rows of 128B; 2 rounds.
    // T2 swizzle: 16B slot ^= (row&7); source pre-swizzled, LDS dest linear.
    const int srow = tid >> 3;                                  // 0..63
    const int scolE = (((tid & 7) ^ (srow & 7)) << 3);          // pre-swizzled source col
    const int sdst = (tid & ~63) * 8;                           // wave-uniform elem offset

    auto stageB = [&](int t, int buf) {
        #pragma unroll
        for (int rnd = 0; rnd < 2; ++rnd) {
            const ushort_t* g = Wf + (size_t)(nBase + rnd * 64 + srow) * K_DIM
                                   + (size_t)t * BK + scolE;
            llds16(g, &Bs[buf][rnd * 4096 + sdst]);
        }
    };

    // A-fragment loads: global->VGPR from fragment-ordered Af2.
    // a[m][kk] = rows (mBase+wr+m*16)+fr, k = t*64 + kk*32 + kg*8..+8.
    // Each instr: 64 lanes x 16B = 1KB contiguous.
    const ushort_t* A2base = Af2 + (size_t)((mBase + wr) >> 4) * NKT * 1024 + lane * 8;
    auto aload = [&](int t, short8 (&a)[4][2]) {
        #pragma unroll
        for (int m = 0; m < 4; ++m)
            #pragma unroll
            for (int kk = 0; kk < 2; ++kk)
                a[m][kk] = *(const short8*)(A2base
                            + ((size_t)m * NKT + t) * 1024 + kk * 512);
    };

    // B read-side swizzled 16B-slot offsets (row&7 == fr&7)
    const int swz0 = ((kg ^ (fr & 7)) << 3);          // kk = 0
    const int swz1 = (((4 + kg) ^ (fr & 7)) << 3);    // kk = 1

    f32x4 acc[4][4];
    #pragma unroll
    for (int m = 0; m < 4; ++m)
        #pragma unroll
        for (int n = 0; n < 4; ++n) acc[m][n] = (f32x4){0.f, 0.f, 0.f, 0.f};

    short8 aA[4][2], aB[4][2];   // register-double-buffered A fragments

    // prologue: a(0)->aA, B(0)->buf0
    aload(0, aA);
    stageB(0, 0);

    // per-tile body: one vmcnt(0)+barrier at top (full-tile lead), issue
    // next a/B, 8 b ds_reads, lgkmcnt(4) -> 16 MFMA, lgkmcnt(0) -> 16 MFMA.
    auto tile = [&](int t, short8 (&aC)[4][2], short8 (&aN)[4][2]) {
        asm volatile("s_waitcnt vmcnt(0)" ::: "memory");
        __builtin_amdgcn_s_barrier();
        __builtin_amdgcn_sched_barrier(0);

        if (t + 1 < NKT) {
            aload(t + 1, aN);
            stageB(t + 1, (t + 1) & 1);
        }
        __builtin_amdgcn_sched_barrier(0);

        const ushort_t* B_ = Bs[t & 1];
        short8 b[4][2];
        #pragma unroll
        for (int n = 0; n < 4; ++n) {
            int brow = (wc + n * 16 + fr) * BK;
            b[n][0] = *(const short8*)&B_[brow + swz0];
            b[n][1] = *(const short8*)&B_[brow + swz1];
        }
        asm volatile("s_waitcnt lgkmcnt(4)" ::: "memory");   // b[0..1] done
        __builtin_amdgcn_sched_barrier(0);
        __builtin_amdgcn_s_setprio(1);
        #pragma unroll
        for (int m = 0; m < 4; ++m)
            #pragma unroll
            for (int n = 0; n < 2; ++n) {
                acc[m][n] = MFMA(aC[m][0], b[n][0], acc[m][n]);
                acc[m][n] = MFMA(aC[m][1], b[n][1], acc[m][n]);
            }
        __builtin_amdgcn_s_setprio(0);
        asm volatile("s_waitcnt lgkmcnt(0)" ::: "memory");   // b[2..3] done
        __builtin_amdgcn_sched_barrier(0);
        __builtin_amdgcn_s_setprio(1);
        #pragma unroll
        for (int m = 0; m < 4; ++m)
            #pragma unroll
            for (int n = 0; n < 2; ++n) {
                acc[m][2 + n] = MFMA(aC[m][0], b[2 + n][0], acc[m][2 + n]);
                acc[m][2 + n] = MFMA(aC[m][1], b[2 + n][1], acc[m][2 + n]);
            }
        __builtin_amdgcn_s_setprio(0);
    };

    for (int t = 0; t < NKT; t += 2) {   // NKT=144 even: reg ping-pong via unroll-2
        tile(t, aA, aB);
        tile(t + 1, aB, aA);
    }

    // epilogue: C/D layout col=lane&15, row=(lane>>4)*4+r  (identical to r4)
    const int orow = (lane >> 4) * 4;
    const int ocol = lane & 15;
    #pragma unroll
    for (int m = 0; m < 4; ++m)
        #pragma unroll
        for (int n = 0; n < 4; ++n) {
            size_t base = (size_t)(mBase + wr + m * 16 + orow) * O_DIM
                        + (nBase + wc + n * 16 + ocol);
            #pragma unroll
            for (int r = 0; r < 4; ++r)
                out[base + (size_t)r * O_DIM] = acc[m][n][r];
        }
}

extern "C" void kernel_launch(void* const* d_in, const int* in_sizes, int n_in,
                              void* d_out, int out_size, void* d_ws, size_t ws_size,
                              hipStream_t stream) {
    const float* x  = (const float*)d_in[0];
    const float* bw = (const float*)d_in[1];
    const float* sw = (const float*)d_in[2];
    float* out = (float*)d_out;

    // ws layout: Wf [1024 x 9216] bf16 (18.9 MB) then Af2 [frag-ordered,
    // 8192*9216 elems] bf16 (151 MB)
    ushort_t* Wf = (ushort_t*)d_ws;
    ushort_t* Af2 = Wf + (size_t)O_DIM * K_DIM;

    expand_w_kernel<<<(O_DIM * I_DIM / 2) / 256, 256, 0, stream>>>(bw, sw, Wf);
    expand_a_kernel<<<(B_DIM * I_DIM / 2) / 256, 256, 0, stream>>>(x, Af2);
    gemm_bt<<<(B_DIM / BM) * (O_DIM / BN), 512, 0, stream>>>(Af2, Wf, out);
}

// Round 12
// 234.441 us; speedup vs baseline: 1.7402x; 1.2651x over previous
//
#include <hip/hip_runtime.h>
#include <hip/hip_bf16.h>

// KAN layer as augmented GEMM:
//   Af[b, c*1024+i] = c==0 ? silu(x[b,i]) : basis_{c-1}(x[b,i])   (bf16)
//   Wf[o, c*1024+i] = c==0 ? base_w[o,i]  : spline_w[o,i,c-1]     (bf16)
//   out = Af @ Wf^T  (fp32 accum via MFMA)
//
// GEMM (r4 schedule x 2 async blocks/CU):
//   128x128 tile, BK=64, 256 threads / 4 waves 2x2 (64x64/wave, r4
//   fragments+epilogue). A+B dbuf = 64KB LDS -> 2 blocks/CU; the two
//   blocks' barriers are independent -> when one drains, the other's
//   waves fill the SIMDs (r3/m114 mechanism). Per tile: vmcnt(0)+barrier
//   at top (1-tile staging lead), p1{stageA(t+1), 12 reads, lgkmcnt(0),
//   16 MFMA}, barrier, p2{stageB(t+1), 4 reads, lgkmcnt(0), 16 MFMA}.
//   (row&7) 16B-slot XOR swizzle (0-conflict @BK=64). Grid 512 = 2/CU,
//   no split-K. XCD swizzle: 64 contiguous wgid/XCD (8bm x 8bn resident
//   -> A-panel L2 reuse).
#define B_DIM 8192
#define I_DIM 1024
#define O_DIM 1024
#define K_DIM 9216   // 9 * 1024

#define BM 128
#define BN 128
#define BK 64
#define NKT (K_DIM / BK)   // 144

typedef unsigned short ushort_t;
typedef __attribute__((ext_vector_type(8))) short short8;
typedef __attribute__((ext_vector_type(4))) float f32x4;

#define MFMA(a, b, c) __builtin_amdgcn_mfma_f32_16x16x32_bf16((a), (b), (c), 0, 0, 0)

__device__ __forceinline__ ushort_t f2bf(float f) {
    unsigned u = __float_as_uint(f);
    unsigned r = 0x7fffu + ((u >> 16) & 1u);
    return (ushort_t)((u + r) >> 16);
}

__device__ __forceinline__ void llds16(const ushort_t* g, ushort_t* l) {
    __builtin_amdgcn_global_load_lds(
        (const __attribute__((address_space(1))) unsigned int*)g,
        (__attribute__((address_space(3))) unsigned int*)l,
        16, 0, 0);
}

// ---------------- expansion: weights ----------------
__global__ __launch_bounds__(256) void expand_w_kernel(
        const float* __restrict__ bw, const float* __restrict__ sw,
        ushort_t* __restrict__ Wf) {
    int idx = blockIdx.x * 256 + threadIdx.x;   // one thread: (o, 2 consecutive i)
    int o = idx >> 9;
    int i = (idx & 511) << 1;
    ushort_t* out = Wf + (size_t)o * K_DIM + i;
    const float* bp = bw + ((size_t)o << 10) + i;
    *(unsigned*)out = (unsigned)f2bf(bp[0]) | ((unsigned)f2bf(bp[1]) << 16);
    const float* sp = sw + (((size_t)o << 10) + i) * 8;   // 16 contiguous floats
    float v[16];
    #pragma unroll
    for (int n = 0; n < 16; ++n) v[n] = sp[n];
    #pragma unroll
    for (int n = 0; n < 8; ++n)
        *(unsigned*)(out + (size_t)(n + 1) * 1024) =
            (unsigned)f2bf(v[n]) | ((unsigned)f2bf(v[8 + n]) << 16);
}

// ---------------- expansion: activations (row-major, coalesced) ----------------
__global__ __launch_bounds__(256) void expand_a_kernel(
        const float* __restrict__ x, ushort_t* __restrict__ Af) {
    int idx = blockIdx.x * 256 + threadIdx.x;   // one thread: (b, 2 consecutive i)
    int b = idx >> 9;
    int i = (idx & 511) << 1;
    const float* xp = x + ((size_t)b << 10) + i;
    float x0 = xp[0], x1 = xp[1];
    ushort_t* out = Af + (size_t)b * K_DIM + i;
    float s0 = x0 / (1.0f + __expf(-x0));
    float s1 = x1 / (1.0f + __expf(-x1));
    *(unsigned*)out = (unsigned)f2bf(s0) | ((unsigned)f2bf(s1) << 16);
    // quadratic B-spline basis, uniform knots -9..9 step 1.8
    float t0 = (x0 + 9.0f) * (1.0f / 1.8f);
    float t1 = (x1 + 9.0f) * (1.0f / 1.8f);
    float fj0 = floorf(t0), fj1 = floorf(t1);
    int j0 = (int)fj0, j1 = (int)fj1;
    float u0 = t0 - fj0, u1 = t1 - fj1;
    float p0 = 0.5f * (1.f - u0) * (1.f - u0);
    float p1 = 0.5f * (-2.f * u0 * u0 + 2.f * u0 + 1.f);
    float p2 = 0.5f * u0 * u0;
    float q0 = 0.5f * (1.f - u1) * (1.f - u1);
    float q1 = 0.5f * (-2.f * u1 * u1 + 2.f * u1 + 1.f);
    float q2 = 0.5f * u1 * u1;
    #pragma unroll
    for (int n = 0; n < 8; ++n) {
        float v0 = (n == j0 - 2) ? p0 : (n == j0 - 1) ? p1 : (n == j0) ? p2 : 0.f;
        float v1 = (n == j1 - 2) ? q0 : (n == j1 - 1) ? q1 : (n == j1) ? q2 : 0.f;
        *(unsigned*)(out + (size_t)(n + 1) * 1024) =
            (unsigned)f2bf(v0) | ((unsigned)f2bf(v1) << 16);
    }
}

// ---------------- GEMM: out[M=8192, N=1024] = Af[M,K] * Wf[N,K]^T ----------------
__global__ __launch_bounds__(256, 2) void gemm_bt(
        const ushort_t* __restrict__ Af,
        const ushort_t* __restrict__ Wf,
        float* __restrict__ out) {
    // A dbuf 32KB + B dbuf 32KB = 64KB -> 2 blocks/CU
    __shared__ __align__(16) ushort_t As[2][BM * BK];
    __shared__ __align__(16) ushort_t Bs[2][BN * BK];

    const int tid = threadIdx.x;

    // T1: bijective XCD swizzle (512 % 8 == 0): XCD owns 64 contiguous wgid
    // = 8 bm x 8 bn -> A-panels and B-panels L2-shared within the XCD.
    const int orig = blockIdx.x;
    const int wgid = (orig & 7) * 64 + (orig >> 3);
    const int bm = wgid >> 3;               // 0..63
    const int bn = wgid & 7;                // 0..7
    const int mBase = bm * BM, nBase = bn * BN;

    const int lane = tid & 63;
    const int w = tid >> 6;                 // 4 waves: 2M x 2N -> 64x64 per wave
    const int wr = (w >> 1) * 64, wc = (w & 1) * 64;
    const int fr = lane & 15;
    const int kg = lane >> 4;               // k-group 0..3

    // staging: 256 threads x 16B = 4KB/round = 32 rows of 128B; 4 rounds each.
    // T2 swizzle: 16B slot ^= (row&7); source pre-swizzled, LDS dest linear.
    const int srow = tid >> 3;                                  // 0..31
    const int scolE = (((tid & 7) ^ (srow & 7)) << 3);          // pre-swizzled source col
    const int sdst = (tid >> 6) * 512;                          // wave-uniform elem offset

    auto stageA = [&](int t, int buf) {
        #pragma unroll
        for (int rnd = 0; rnd < 4; ++rnd) {
            const ushort_t* g = Af + (size_t)(mBase + rnd * 32 + srow) * K_DIM
                                   + (size_t)t * BK + scolE;
            llds16(g, &As[buf][rnd * 2048 + sdst]);
        }
    };
    auto stageB = [&](int t, int buf) {
        #pragma unroll
        for (int rnd = 0; rnd < 4; ++rnd) {
            const ushort_t* g = Wf + (size_t)(nBase + rnd * 32 + srow) * K_DIM
                                   + (size_t)t * BK + scolE;
            llds16(g, &Bs[buf][rnd * 2048 + sdst]);
        }
    };

    // read-side swizzled 16B-slot offsets (row&7 == fr&7; wr/wc/16m mult of 16)
    const int swz0 = ((kg ^ (fr & 7)) << 3);          // kk = 0
    const int swz1 = (((4 + kg) ^ (fr & 7)) << 3);    // kk = 1

    f32x4 acc[4][4];
    #pragma unroll
    for (int m = 0; m < 4; ++m)
        #pragma unroll
        for (int n = 0; n < 4; ++n) acc[m][n] = (f32x4){0.f, 0.f, 0.f, 0.f};

    // prologue: tile 0 -> buf 0
    stageA(0, 0);
    stageB(0, 0);

    for (int t = 0; t < NKT; ++t) {
        const int cur = t & 1, nb = cur ^ 1;
        // tile t's stages (issued in tile t-1) are the only outstanding ops
        asm volatile("s_waitcnt vmcnt(0)" ::: "memory");
        __builtin_amdgcn_s_barrier();

        const ushort_t* A_ = As[cur];
        const ushort_t* B_ = Bs[cur];

        // ---- p1: issue stageA(t+1); read a[4][2]+b0[2][2] (12); 16 MFMA ----
        if (t + 1 < NKT) stageA(t + 1, nb);
        __builtin_amdgcn_sched_barrier(0);
        short8 a[4][2], b0[2][2], b1[2][2];
        #pragma unroll
        for (int m = 0; m < 4; ++m) {
            int arow = (wr + m * 16 + fr) * BK;
            a[m][0] = *(const short8*)&A_[arow + swz0];
            a[m][1] = *(const short8*)&A_[arow + swz1];
        }
        #pragma unroll
        for (int n = 0; n < 2; ++n) {
            int brow = (wc + n * 16 + fr) * BK;
            b0[n][0] = *(const short8*)&B_[brow + swz0];
            b0[n][1] = *(const short8*)&B_[brow + swz1];
        }
        asm volatile("s_waitcnt lgkmcnt(0)" ::: "memory");
        __builtin_amdgcn_sched_barrier(0);
        __builtin_amdgcn_s_setprio(1);
        #pragma unroll
        for (int m = 0; m < 4; ++m)
            #pragma unroll
            for (int n = 0; n < 2; ++n) {
                acc[m][n] = MFMA(a[m][0], b0[n][0], acc[m][n]);
                acc[m][n] = MFMA(a[m][1], b0[n][1], acc[m][n]);
            }
        __builtin_amdgcn_s_setprio(0);
        __builtin_amdgcn_s_barrier();

        // ---- p2: issue stageB(t+1); read b1[2][2] (4); 16 MFMA ----
        if (t + 1 < NKT) stageB(t + 1, nb);
        __builtin_amdgcn_sched_barrier(0);
        #pragma unroll
        for (int n = 0; n < 2; ++n) {
            int brow = (wc + (2 + n) * 16 + fr) * BK;
            b1[n][0] = *(const short8*)&B_[brow + swz0];
            b1[n][1] = *(const short8*)&B_[brow + swz1];
        }
        asm volatile("s_waitcnt lgkmcnt(0)" ::: "memory");
        __builtin_amdgcn_sched_barrier(0);
        __builtin_amdgcn_s_setprio(1);
        #pragma unroll
        for (int m = 0; m < 4; ++m)
            #pragma unroll
            for (int n = 0; n < 2; ++n) {
                acc[m][2 + n] = MFMA(a[m][0], b1[n][0], acc[m][2 + n]);
                acc[m][2 + n] = MFMA(a[m][1], b1[n][1], acc[m][2 + n]);
            }
        __builtin_amdgcn_s_setprio(0);
    }

    // epilogue: C/D layout col=lane&15, row=(lane>>4)*4+r
    const int orow = (lane >> 4) * 4;
    const int ocol = lane & 15;
    #pragma unroll
    for (int m = 0; m < 4; ++m)
        #pragma unroll
        for (int n = 0; n < 4; ++n) {
            size_t base = (size_t)(mBase + wr + m * 16 + orow) * O_DIM
                        + (nBase + wc + n * 16 + ocol);
            #pragma unroll
            for (int r = 0; r < 4; ++r)
                out[base + (size_t)r * O_DIM] = acc[m][n][r];
        }
}

extern "C" void kernel_launch(void* const* d_in, const int* in_sizes, int n_in,
                              void* d_out, int out_size, void* d_ws, size_t ws_size,
                              hipStream_t stream) {
    const float* x  = (const float*)d_in[0];
    const float* bw = (const float*)d_in[1];
    const float* sw = (const float*)d_in[2];
    float* out = (float*)d_out;

    // ws layout: Wf [1024 x 9216] bf16 (18.9 MB) then Af [8192 x 9216] bf16 (151 MB)
    ushort_t* Wf = (ushort_t*)d_ws;
    ushort_t* Af = Wf + (size_t)O_DIM * K_DIM;

    expand_w_kernel<<<(O_DIM * I_DIM / 2) / 256, 256, 0, stream>>>(bw, sw, Wf);
    expand_a_kernel<<<(B_DIM * I_DIM / 2) / 256, 256, 0, stream>>>(x, Af);
    gemm_bt<<<(B_DIM / BM) * (O_DIM / BN), 256, 0, stream>>>(Af, Wf, out);
}